// Round 8
// baseline (220.010 us; speedup 1.0000x reference)
//
#include <hip/hip_runtime.h>
#include <math.h>

// [SQ, B, NP, HN] fp32, unscaled QK^T softmax attention.
#define SQ 2048
#define NBH 32           // B*NP heads
#define HN 64
#define BQ 64            // queries per block = 4 waves x 16
#define QW 16            // queries per wave (16x16 MFMA)
#define BK2 128          // keys per phase
#define NPH2 16          // phases
#define TOK 2048         // floats between consecutive tokens
#define VTILE 8192       // halfs per 128-key V tile image (16 KB)

typedef _Float16 half2v __attribute__((ext_vector_type(2)));
typedef _Float16 half8v __attribute__((ext_vector_type(8)));
typedef float f32x4 __attribute__((ext_vector_type(4)));

__device__ __forceinline__ void async16(const void* g, void* l) {
  __builtin_amdgcn_global_load_lds(
      (const __attribute__((address_space(1))) void*)g,
      (__attribute__((address_space(3))) void*)l, 16, 0, 0);
}
__device__ __forceinline__ float fexp2(float x) {
#if __has_builtin(__builtin_amdgcn_exp2f)
  return __builtin_amdgcn_exp2f(x);
#else
  return exp2f(x);
#endif
}

// prep: Kh f16 [head][key][dim] plain rows (x log2e).  Vt: per head, 16 tile
// images of 16 KB; image: row d (256B) holds 16B unit w=4*ks+gg at pos16=w^(d&15);
// unit halfs j<4 -> key 32ks+4gg+j, j>=4 -> key 32ks+16+4gg+(j-4)  (the exact
// A-operand order of the PV MFMA -> one ds_read_b128 per fragment).
__global__ __launch_bounds__(256) void prep_kv(const float* __restrict__ K,
                                               const float* __restrict__ V,
                                               _Float16* __restrict__ Kh,
                                               _Float16* __restrict__ Vt) {
  __shared__ _Float16 vs[VTILE];
  const int t = threadIdx.x;
  const int head = blockIdx.y;
  const int kt0 = blockIdx.x * 128;
  const float LOG2E = 1.44269504088896f;
  // K: thread covers 32 dims of one key
  {
    const int key = kt0 + (t >> 1);
    const int d0 = (t & 1) * 32;
    const float* src = K + (size_t)key * TOK + head * HN + d0;
    _Float16* dst = Kh + ((size_t)head * SQ + key) * HN + d0;
    #pragma unroll
    for (int i = 0; i < 4; ++i) {
      float4 a = *(const float4*)(src + i * 8);
      float4 b = *(const float4*)(src + i * 8 + 4);
      half8v h;
      h[0]=(_Float16)(LOG2E*a.x); h[1]=(_Float16)(LOG2E*a.y);
      h[2]=(_Float16)(LOG2E*a.z); h[3]=(_Float16)(LOG2E*a.w);
      h[4]=(_Float16)(LOG2E*b.x); h[5]=(_Float16)(LOG2E*b.y);
      h[6]=(_Float16)(LOG2E*b.z); h[7]=(_Float16)(LOG2E*b.w);
      *(half8v*)(dst + i * 8) = h;
    }
  }
  // V: stage full tile image in LDS (scattered half2 writes), then linear copy
  #pragma unroll
  for (int tau = 0; tau < 2; ++tau) {
    const int task = t + tau * 256;
    const int k2 = (task & 63) * 2;          // even key (r in {0,2})
    const int db = (task >> 6) * 8;
    const float* src = V + (size_t)(kt0 + k2) * TOK + head * HN + db;
    float4 a0 = *(const float4*)src;
    float4 a1 = *(const float4*)(src + 4);
    float4 b0 = *(const float4*)(src + TOK);
    float4 b1 = *(const float4*)(src + TOK + 4);
    const float av[8] = {a0.x,a0.y,a0.z,a0.w,a1.x,a1.y,a1.z,a1.w};
    const float bv[8] = {b0.x,b0.y,b0.z,b0.w,b1.x,b1.y,b1.z,b1.w};
    const int ks = k2 >> 5, gg = (k2 >> 2) & 3, hh = (k2 >> 4) & 1, r = k2 & 3;
    #pragma unroll
    for (int j = 0; j < 8; ++j) {
      const int d = db + j;
      const int pos = (4 * ks + gg) ^ (d & 15);
      half2v h; h[0] = (_Float16)av[j]; h[1] = (_Float16)bv[j];
      *(half2v*)&vs[d * 128 + pos * 8 + hh * 4 + r] = h;
    }
  }
  __syncthreads();
  _Float16* dst = Vt + ((size_t)head * NPH2 + blockIdx.x) * VTILE;
  #pragma unroll
  for (int i = 0; i < 4; ++i) {
    const int idx = i * 256 + t;
    *(half8v*)(dst + idx * 8) = *(const half8v*)&vs[idx * 8];
  }
}

// main: 16 q/wave flash attention. S^T = K.Q^T via mfma_16x16x32_f16:
// C: col=lane&15(query), row=(lane>>4)*4+reg(key). A/B: k-slot=(lane>>4)*8+j.
// K frags straight from global (L1-shared in block); V via DMA dbuf in LDS;
// P^T stays in registers (permuted-k PV). 4 blocks/CU, 4 waves/SIMD.
__global__ __launch_bounds__(256, 4)
void fattn_mfma(const float* __restrict__ Q, const _Float16* __restrict__ Kh,
                const _Float16* __restrict__ Vt, float* __restrict__ O) {
  __shared__ __align__(16) _Float16 vtf[2][VTILE];
  const int t = threadIdx.x;
  const int lane = t & 63;
  const int w = t >> 6;
  const int n = lane & 15;          // query column
  const int g = lane >> 4;          // 0..3
  const int qb = blockIdx.x * BQ + w * QW;
  const int head = blockIdx.y;
  const _Float16* Kp = Kh + (size_t)head * SQ * HN;
  const _Float16* Vp = Vt + (size_t)head * NPH2 * VTILE;

  // Q B-frags: B[kslot=8g+j][n] = Q[qb+n][32ks+8g+j]  (f32->f16, no scale)
  half8v qf[2];
  {
    const float* qp = Q + (size_t)(qb + n) * TOK + head * HN + 8 * g;
    #pragma unroll
    for (int ks = 0; ks < 2; ++ks) {
      float4 a = *(const float4*)(qp + 32 * ks);
      float4 b = *(const float4*)(qp + 32 * ks + 4);
      half8v f;
      f[0]=(_Float16)a.x; f[1]=(_Float16)a.y; f[2]=(_Float16)a.z; f[3]=(_Float16)a.w;
      f[4]=(_Float16)b.x; f[5]=(_Float16)b.y; f[6]=(_Float16)b.z; f[7]=(_Float16)b.w;
      qf[ks] = f;
    }
  }

  f32x4 acc[4];                      // O^T frags: dim tiles 0..3
  #pragma unroll
  for (int dt = 0; dt < 4; ++dt) acc[dt] = (f32x4){0.f, 0.f, 0.f, 0.f};
  float m_i = -INFINITY, l_i = 0.f;

  auto stage = [&](int p) {          // pure DMA: 4 x 16B per thread
    const _Float16* src = Vp + (size_t)p * VTILE;
    #pragma unroll
    for (int i = 0; i < 4; ++i) {
      const int idx = i * 256 + t;
      async16(src + idx * 8, &vtf[p & 1][idx * 8]);
    }
  };

  stage(0);
  for (int p = 0; p < NPH2; ++p) {
    __syncthreads();                 // drains DMA for buf p&1; prior readers done
    if (p + 1 < NPH2) stage(p + 1);
    const int cur = p & 1;

    // ---- S^T = K.Q^T: 8 key-tiles x 2 ksteps; K frags from global ----
    f32x4 sf[8];
    #pragma unroll
    for (int ks = 0; ks < 2; ++ks) {
      half8v kf[8];
      #pragma unroll
      for (int kt = 0; kt < 8; ++kt)
        kf[kt] = *(const half8v*)(Kp + (size_t)(p * BK2 + kt * 16 + n) * HN +
                                  32 * ks + 8 * g);
      #pragma unroll
      for (int kt = 0; kt < 8; ++kt) {
        f32x4 c = (ks == 0) ? (f32x4){0.f, 0.f, 0.f, 0.f} : sf[kt];
        sf[kt] = __builtin_amdgcn_mfma_f32_16x16x32_f16(kf[kt], qf[ks], c, 0, 0, 0);
      }
    }

    // ---- online softmax (log2 domain; 4 lanes/query -> 2 shfls) ----
    float mx = -INFINITY;
    #pragma unroll
    for (int kt = 0; kt < 8; ++kt)
      mx = fmaxf(mx, fmaxf(fmaxf(sf[kt][0], sf[kt][1]), fmaxf(sf[kt][2], sf[kt][3])));
    mx = fmaxf(mx, __shfl_xor(mx, 16, 64));
    mx = fmaxf(mx, __shfl_xor(mx, 32, 64));
    const float mnew = fmaxf(m_i, mx);
    const float alpha = fexp2(m_i - mnew);   // 0 on first phase
    float rsum = 0.f;
    #pragma unroll
    for (int kt = 0; kt < 8; ++kt) {
      float p0 = fexp2(sf[kt][0] - mnew);
      float p1 = fexp2(sf[kt][1] - mnew);
      float p2 = fexp2(sf[kt][2] - mnew);
      float p3 = fexp2(sf[kt][3] - mnew);
      sf[kt][0] = p0; sf[kt][1] = p1; sf[kt][2] = p2; sf[kt][3] = p3;
      rsum += (p0 + p1) + (p2 + p3);
    }
    rsum += __shfl_xor(rsum, 16, 64);
    rsum += __shfl_xor(rsum, 32, 64);
    l_i = l_i * alpha + rsum;
    m_i = mnew;
    #pragma unroll
    for (int dt = 0; dt < 4; ++dt) acc[dt] *= alpha;

    // ---- PV: O^T += V^T.P^T, permuted k: slot(g,j) -> key 32ks+{4g+j | 16+4g+j-4} ----
    #pragma unroll
    for (int ks = 0; ks < 4; ++ks) {
      union { half8v v8; half2v v2[4]; } pu;
      auto c0 = __builtin_amdgcn_cvt_pkrtz(sf[2*ks][0],   sf[2*ks][1]);
      auto c1 = __builtin_amdgcn_cvt_pkrtz(sf[2*ks][2],   sf[2*ks][3]);
      auto c2 = __builtin_amdgcn_cvt_pkrtz(sf[2*ks+1][0], sf[2*ks+1][1]);
      auto c3 = __builtin_amdgcn_cvt_pkrtz(sf[2*ks+1][2], sf[2*ks+1][3]);
      pu.v2[0] = *(half2v*)&c0; pu.v2[1] = *(half2v*)&c1;
      pu.v2[2] = *(half2v*)&c2; pu.v2[3] = *(half2v*)&c3;
      const int pos = (4 * ks + g) ^ n;
      const _Float16* vb = &vtf[cur][n * 128 + pos * 8];
      #pragma unroll
      for (int dt = 0; dt < 4; ++dt) {
        half8v av = *(const half8v*)(vb + dt * 2048);   // row d = 16*dt + n
        acc[dt] = __builtin_amdgcn_mfma_f32_16x16x32_f16(av, pu.v8, acc[dt], 0, 0, 0);
      }
    }
  }

  // ---- epilogue: dim = 16*dt + 4*g + r ----
  const float invl = 1.f / l_i;
  float* orow = O + (size_t)(qb + n) * TOK + head * HN;
  #pragma unroll
  for (int dt = 0; dt < 4; ++dt)
    #pragma unroll
    for (int r = 0; r < 4; ++r)
      orow[16 * dt + 4 * g + r] = acc[dt][r] * invl;
}

extern "C" void kernel_launch(void* const* d_in, const int* in_sizes, int n_in,
                              void* d_out, int out_size, void* d_ws, size_t ws_size,
                              hipStream_t stream) {
  const float* Q = (const float*)d_in[0];
  const float* K = (const float*)d_in[1];
  const float* V = (const float*)d_in[2];
  float* O = (float*)d_out;
  _Float16* Kh = (_Float16*)d_ws;                       // 8 MB
  _Float16* Vh = Kh + (size_t)NBH * SQ * HN;            // 8 MB
  prep_kv<<<dim3(NPH2, NBH), 256, 0, stream>>>(K, V, Kh, Vh);
  fattn_mfma<<<dim3(SQ / BQ, NBH), 256, 0, stream>>>(Q, Kh, Vh, O);
}

// Round 9
// 153.244 us; speedup vs baseline: 1.4357x; 1.4357x over previous
//
#include <hip/hip_runtime.h>
#include <math.h>

// [SQ, B, NP, HN] fp32, unscaled QK^T softmax attention.
#define SQ 2048
#define NBH 32           // B*NP heads
#define HN 64
#define BQ 128           // queries per block (4 waves x 32)
#define BK 64            // keys per phase
#define NSPLIT 2         // key-range splits (split-K)
#define KSPLIT (SQ/NSPLIT)
#define NPH (KSPLIT/BK)  // 16 phases per block
#define TOK 2048         // floats between consecutive tokens
#define HSTRIDE (SQ*HN)  // halfs per head in f16 scratch

typedef _Float16 half2v __attribute__((ext_vector_type(2)));
typedef _Float16 half4v __attribute__((ext_vector_type(4)));
typedef _Float16 half8v __attribute__((ext_vector_type(8)));
typedef float f32x16 __attribute__((ext_vector_type(16)));

__device__ __forceinline__ void async16(const void* g, void* l) {
  __builtin_amdgcn_global_load_lds(
      (const __attribute__((address_space(1))) void*)g,
      (__attribute__((address_space(3))) void*)l, 16, 0, 0);
}
__device__ __forceinline__ float fexp2(float x) {
#if __has_builtin(__builtin_amdgcn_exp2f)
  return __builtin_amdgcn_exp2f(x);
#else
  return exp2f(x);
#endif
}

// ---- prep (R7-verbatim): Kh f16 [head][key][dim], 16B chunks xor-swizzled by
// key&7 within each 128B row.  Vt f16 [head][dim][key], 4-key units
// xor-swizzled by dim&15 within each 64-key tile.
__global__ __launch_bounds__(256) void prep_kv(const float* __restrict__ K,
                                               const float* __restrict__ V,
                                               _Float16* __restrict__ Kh,
                                               _Float16* __restrict__ Vt) {
  __shared__ _Float16 vs[HN * 64];
  const int t = threadIdx.x;
  const int head = blockIdx.y;
  {
    const int key = blockIdx.x * 64 + (t >> 2);
    const int c0 = (t & 3) * 2;
    const float* src = K + (size_t)key * TOK + head * HN + c0 * 8;
    float4 a = *(const float4*)src;
    float4 b = *(const float4*)(src + 4);
    float4 c = *(const float4*)(src + 8);
    float4 d = *(const float4*)(src + 12);
    half8v h0, h1;
    h0[0]=(_Float16)a.x; h0[1]=(_Float16)a.y; h0[2]=(_Float16)a.z; h0[3]=(_Float16)a.w;
    h0[4]=(_Float16)b.x; h0[5]=(_Float16)b.y; h0[6]=(_Float16)b.z; h0[7]=(_Float16)b.w;
    h1[0]=(_Float16)c.x; h1[1]=(_Float16)c.y; h1[2]=(_Float16)c.z; h1[3]=(_Float16)c.w;
    h1[4]=(_Float16)d.x; h1[5]=(_Float16)d.y; h1[6]=(_Float16)d.z; h1[7]=(_Float16)d.w;
    _Float16* row = Kh + (size_t)head * HSTRIDE + (size_t)key * 64;
    *(half8v*)&row[((c0    ) ^ (key & 7)) * 8] = h0;
    *(half8v*)&row[((c0 + 1) ^ (key & 7)) * 8] = h1;
  }
  {
    const int kt = blockIdx.x * 64;
    const int kl = (t >> 3) * 2;
    const int db = (t & 7) * 8;
    const float* src = V + (size_t)(kt + kl) * TOK + head * HN + db;
    float4 a0 = *(const float4*)src;
    float4 a1 = *(const float4*)(src + 4);
    float4 b0 = *(const float4*)(src + TOK);
    float4 b1 = *(const float4*)(src + TOK + 4);
    const float av[8] = {a0.x,a0.y,a0.z,a0.w,a1.x,a1.y,a1.z,a1.w};
    const float bv[8] = {b0.x,b0.y,b0.z,b0.w,b1.x,b1.y,b1.z,b1.w};
    const int u = kl >> 2;
    #pragma unroll
    for (int j = 0; j < 8; ++j) {
      const int dim = db + j;
      const int pos = u ^ (dim & 15);
      half2v h; h[0] = (_Float16)av[j]; h[1] = (_Float16)bv[j];
      *(half2v*)&vs[dim * 64 + pos * 4 + (kl & 3)] = h;
    }
    __syncthreads();
    const int dim = t >> 2;
    const int q = (t & 3) ^ (dim & 3);
    const _Float16* srow = &vs[dim * 64 + q * 16];
    _Float16* drow = Vt + (size_t)head * HSTRIDE + (size_t)dim * SQ + kt + q * 16;
    *(half8v*)&drow[0] = *(const half8v*)&srow[0];
    *(half8v*)&drow[8] = *(const half8v*)&srow[8];
  }
}

// ---- main (split-K): S^T = K.Q^T via mfma_32x32x16_f16 (R6 math verbatim).
// C layout: col=lane&31, row=(reg&3)+8*(reg>>2)+4*(lane>>5). P^T stays in regs.
// blockIdx.z = key-range split. Writes unnormalized acc (f16) + (m,l).
// 32 KB LDS dbuf -> 4 blocks/CU, 16 waves/CU, 4 waves/SIMD.
__global__ __launch_bounds__(256, 4)
void fattn_mfma(const float* __restrict__ Q, const _Float16* __restrict__ Kh,
                const _Float16* __restrict__ Vt, _Float16* __restrict__ Op,
                float2* __restrict__ ML) {
  __shared__ __align__(16) _Float16 kbf[2][BK * 64];
  __shared__ __align__(16) _Float16 vtf[2][HN * 64];

  const int t = threadIdx.x;
  const int lane = t & 63;
  const int w = t >> 6;
  const int h2 = lane >> 5;
  const int l31 = lane & 31;
  const int qb = blockIdx.x * BQ + w * 32;
  const int head = blockIdx.y;
  const int sp = blockIdx.z;
  const int koff = sp * KSPLIT;
  const _Float16* Kp = Kh + (size_t)head * HSTRIDE;
  const _Float16* Vp = Vt + (size_t)head * HSTRIDE;

  // Q B-frags x log2(e): n=query=l31, k=dim=8*h2+j+16*ks
  half8v qf[4];
  {
    const float* qp = Q + (size_t)(qb + l31) * TOK + head * HN + 8 * h2;
    const float s = 1.44269504088896f;
    #pragma unroll
    for (int ks = 0; ks < 4; ++ks) {
      float4 a = *(const float4*)(qp + 16 * ks);
      float4 b = *(const float4*)(qp + 16 * ks + 4);
      half8v f;
      f[0]=(_Float16)(s*a.x); f[1]=(_Float16)(s*a.y); f[2]=(_Float16)(s*a.z); f[3]=(_Float16)(s*a.w);
      f[4]=(_Float16)(s*b.x); f[5]=(_Float16)(s*b.y); f[6]=(_Float16)(s*b.z); f[7]=(_Float16)(s*b.w);
      qf[ks] = f;
    }
  }

  f32x16 acc0, acc1;
  #pragma unroll
  for (int r = 0; r < 16; ++r) { acc0[r] = 0.f; acc1[r] = 0.f; }
  float m_i = -INFINITY, l_i = 0.f;

  auto stage = [&](int p) {     // 16 KB per phase, pure DMA
    const int kt = koff + p * BK;
    const int buf = p & 1;
    #pragma unroll
    for (int i = 0; i < 2; ++i) {
      const int off = w * 1024 + i * 512;
      async16(Kp + (size_t)kt * 64 + off + lane * 8, &kbf[buf][off]);
    }
    #pragma unroll
    for (int i = 0; i < 2; ++i) {
      const int off = w * 1024 + i * 512;
      const int eo = off + lane * 8;
      const int dim = eo >> 6, inner = eo & 63;
      async16(Vp + (size_t)dim * SQ + kt + inner, &vtf[buf][off]);
    }
  };

  stage(0);
  for (int p = 0; p < NPH; ++p) {
    __syncthreads();
    if (p + 1 < NPH) stage(p + 1);
    const int cur = p & 1;

    // ---- S^T = K.Q^T ----
    f32x16 sf0, sf1;
    {
      f32x16 c0, c1;
      #pragma unroll
      for (int r = 0; r < 16; ++r) { c0[r] = 0.f; c1[r] = 0.f; }
      #pragma unroll
      for (int ks = 0; ks < 4; ++ks) {
        const int pos = ((h2 + 2 * ks) ^ (l31 & 7)) * 8;
        half8v a0v = *(const half8v*)&kbf[cur][l31 * 64 + pos];
        half8v a1v = *(const half8v*)&kbf[cur][(l31 + 32) * 64 + pos];
        c0 = __builtin_amdgcn_mfma_f32_32x32x16_f16(a0v, qf[ks], c0, 0, 0, 0);
        c1 = __builtin_amdgcn_mfma_f32_32x32x16_f16(a1v, qf[ks], c1, 0, 0, 0);
      }
      sf0 = c0; sf1 = c1;
    }

    // ---- online softmax (log2 domain) ----
    float mx = -INFINITY;
    #pragma unroll
    for (int r = 0; r < 16; ++r) mx = fmaxf(mx, fmaxf(sf0[r], sf1[r]));
    mx = fmaxf(mx, __shfl_xor(mx, 32, 64));
    const float mnew = fmaxf(m_i, mx);
    const float alpha = fexp2(m_i - mnew);
    float rsum = 0.f;
    #pragma unroll
    for (int r = 0; r < 16; ++r) {
      float p0 = fexp2(sf0[r] - mnew);
      float p1 = fexp2(sf1[r] - mnew);
      sf0[r] = p0; sf1[r] = p1;
      rsum += p0 + p1;
    }
    rsum += __shfl_xor(rsum, 32, 64);
    l_i = l_i * alpha + rsum;
    m_i = mnew;
    #pragma unroll
    for (int r = 0; r < 16; ++r) { acc0[r] *= alpha; acc1[r] *= alpha; }

    // ---- PV: O^T += V^T.P^T, permuted k-order ----
    #pragma unroll
    for (int ks = 0; ks < 4; ++ks) {
      const int rb = 8 * (ks & 1);
      const f32x16& s = (ks < 2) ? sf0 : sf1;
      union { half8v v8; half2v v2[4]; } pu;
      #pragma unroll
      for (int tt = 0; tt < 4; ++tt) {
        auto pk = __builtin_amdgcn_cvt_pkrtz(s[rb + 2 * tt], s[rb + 2 * tt + 1]);
        pu.v2[tt] = *(half2v*)&pk;
      }
      #pragma unroll
      for (int mbd = 0; mbd < 2; ++mbd) {
        const int dim = l31 + 32 * mbd;
        const int sw = dim & 15;
        union { half8v v8; half4v v4[2]; } au;
        au.v4[0] = *(const half4v*)&vtf[cur][dim * 64 + ((4 * ks + h2)     ^ sw) * 4];
        au.v4[1] = *(const half4v*)&vtf[cur][dim * 64 + ((4 * ks + 2 + h2) ^ sw) * 4];
        if (mbd == 0)
          acc0 = __builtin_amdgcn_mfma_f32_32x32x16_f16(au.v8, pu.v8, acc0, 0, 0, 0);
        else
          acc1 = __builtin_amdgcn_mfma_f32_32x32x16_f16(au.v8, pu.v8, acc1, 0, 0, 0);
      }
    }
  }

  // ---- epilogue: unnormalized partial in f16 + (m,l) per query ----
  _Float16* prow = Op + (((size_t)(sp * NBH + head)) * SQ + qb + l31) * HN;
  #pragma unroll
  for (int rq = 0; rq < 4; ++rq) {   // dims 8*rq+4*h2 .. +3  (r = 4*rq + (r&3))
    half4v h0, h1;
    #pragma unroll
    for (int j = 0; j < 4; ++j) {
      h0[j] = (_Float16)acc0[4 * rq + j];
      h1[j] = (_Float16)acc1[4 * rq + j];
    }
    *(half4v*)&prow[8 * rq + 4 * h2]      = h0;
    *(half4v*)&prow[32 + 8 * rq + 4 * h2] = h1;
  }
  if (h2 == 0) {
    float2 ml; ml.x = m_i; ml.y = l_i;
    ML[((size_t)(sp * NBH + head)) * SQ + qb + l31] = ml;
  }
}

// ---- merge: O = (A0*w0 + A1*w1) / (l0*w0 + l1*w1), wi = 2^(mi - m) ----
__global__ __launch_bounds__(256)
void merge2(const _Float16* __restrict__ Op, const float2* __restrict__ ML,
            float* __restrict__ O) {
  const int gid = blockIdx.x * 256 + threadIdx.x;
  const int f = gid * 4;                 // flat f32 out index
  const int q = f >> 11;
  const int rem = f & 2047;
  const int head = rem >> 6;
  const int d = rem & 63;
  const size_t i0 = (size_t)head * SQ + q;
  const size_t i1 = (size_t)(NBH + head) * SQ + q;
  const float2 ml0 = ML[i0];
  const float2 ml1 = ML[i1];
  const float m = fmaxf(ml0.x, ml1.x);
  const float w0 = fexp2(ml0.x - m);
  const float w1 = fexp2(ml1.x - m);
  const float inv = 1.f / (ml0.y * w0 + ml1.y * w1);
  half4v a0 = *(const half4v*)(Op + i0 * HN + d);
  half4v a1 = *(const half4v*)(Op + i1 * HN + d);
  float4 o;
  o.x = ((float)a0[0] * w0 + (float)a1[0] * w1) * inv;
  o.y = ((float)a0[1] * w0 + (float)a1[1] * w1) * inv;
  o.z = ((float)a0[2] * w0 + (float)a1[2] * w1) * inv;
  o.w = ((float)a0[3] * w0 + (float)a1[3] * w1) * inv;
  *(float4*)(O + f) = o;
}

extern "C" void kernel_launch(void* const* d_in, const int* in_sizes, int n_in,
                              void* d_out, int out_size, void* d_ws, size_t ws_size,
                              hipStream_t stream) {
  const float* Q = (const float*)d_in[0];
  const float* K = (const float*)d_in[1];
  const float* V = (const float*)d_in[2];
  float* O = (float*)d_out;
  _Float16* Kh = (_Float16*)d_ws;                         // 8 MB
  _Float16* Vh = Kh + (size_t)NBH * HSTRIDE;              // 8 MB
  _Float16* Op = Vh + (size_t)NBH * HSTRIDE;              // 16.8 MB
  float2*   ML = (float2*)(Op + (size_t)NSPLIT * NBH * SQ * HN);  // 1 MB
  prep_kv<<<dim3(SQ / 64, NBH), 256, 0, stream>>>(K, V, Kh, Vh);
  fattn_mfma<<<dim3(SQ / BQ, NBH, NSPLIT), 256, 0, stream>>>(Q, Kh, Vh, Op, ML);
  merge2<<<dim3(SQ * NBH * HN / 4 / 256), 256, 0, stream>>>(Op, ML, O);
}

// Round 10
// 151.819 us; speedup vs baseline: 1.4492x; 1.0094x over previous
//
#include <hip/hip_runtime.h>
#include <math.h>

// [SQ, B, NP, HN] fp32, unscaled QK^T softmax attention.
#define SQ 2048
#define NBH 32           // B*NP heads
#define HN 64
#define BQ 128           // queries per block (4 waves x 32)
#define BK 64            // keys per phase
#define NSPLIT 2         // key-range splits (split-K)
#define KSPLIT (SQ/NSPLIT)
#define NPH (KSPLIT/BK)  // 16 phases per block
#define TOK 2048         // floats between consecutive tokens
#define HSTRIDE (SQ*HN)  // halfs per head in f16 scratch

typedef _Float16 half2v __attribute__((ext_vector_type(2)));
typedef _Float16 half4v __attribute__((ext_vector_type(4)));
typedef _Float16 half8v __attribute__((ext_vector_type(8)));
typedef float f32x16 __attribute__((ext_vector_type(16)));

__device__ __forceinline__ void async16(const void* g, void* l) {
  __builtin_amdgcn_global_load_lds(
      (const __attribute__((address_space(1))) void*)g,
      (__attribute__((address_space(3))) void*)l, 16, 0, 0);
}
__device__ __forceinline__ float fexp2(float x) {
#if __has_builtin(__builtin_amdgcn_exp2f)
  return __builtin_amdgcn_exp2f(x);
#else
  return exp2f(x);
#endif
}

// ---- prep: Kh f16 [head][key][dim], 16B chunks xor-swizzled by key&7 within
// each 128B row.  Vt f16 [head][dim][key], 4-key units xor-swizzled by dim&15
// within each 64-key tile.
__global__ __launch_bounds__(256) void prep_kv(const float* __restrict__ K,
                                               const float* __restrict__ V,
                                               _Float16* __restrict__ Kh,
                                               _Float16* __restrict__ Vt) {
  __shared__ _Float16 vs[HN * 64];
  const int t = threadIdx.x;
  const int head = blockIdx.y;
  {
    const int key = blockIdx.x * 64 + (t >> 2);
    const int c0 = (t & 3) * 2;
    const float* src = K + (size_t)key * TOK + head * HN + c0 * 8;
    float4 a = *(const float4*)src;
    float4 b = *(const float4*)(src + 4);
    float4 c = *(const float4*)(src + 8);
    float4 d = *(const float4*)(src + 12);
    half8v h0, h1;
    h0[0]=(_Float16)a.x; h0[1]=(_Float16)a.y; h0[2]=(_Float16)a.z; h0[3]=(_Float16)a.w;
    h0[4]=(_Float16)b.x; h0[5]=(_Float16)b.y; h0[6]=(_Float16)b.z; h0[7]=(_Float16)b.w;
    h1[0]=(_Float16)c.x; h1[1]=(_Float16)c.y; h1[2]=(_Float16)c.z; h1[3]=(_Float16)c.w;
    h1[4]=(_Float16)d.x; h1[5]=(_Float16)d.y; h1[6]=(_Float16)d.z; h1[7]=(_Float16)d.w;
    _Float16* row = Kh + (size_t)head * HSTRIDE + (size_t)key * 64;
    *(half8v*)&row[((c0    ) ^ (key & 7)) * 8] = h0;
    *(half8v*)&row[((c0 + 1) ^ (key & 7)) * 8] = h1;
  }
  {
    const int kt = blockIdx.x * 64;
    const int kl = (t >> 3) * 2;
    const int db = (t & 7) * 8;
    const float* src = V + (size_t)(kt + kl) * TOK + head * HN + db;
    float4 a0 = *(const float4*)src;
    float4 a1 = *(const float4*)(src + 4);
    float4 b0 = *(const float4*)(src + TOK);
    float4 b1 = *(const float4*)(src + TOK + 4);
    const float av[8] = {a0.x,a0.y,a0.z,a0.w,a1.x,a1.y,a1.z,a1.w};
    const float bv[8] = {b0.x,b0.y,b0.z,b0.w,b1.x,b1.y,b1.z,b1.w};
    const int u = kl >> 2;
    #pragma unroll
    for (int j = 0; j < 8; ++j) {
      const int dim = db + j;
      const int pos = u ^ (dim & 15);
      half2v h; h[0] = (_Float16)av[j]; h[1] = (_Float16)bv[j];
      *(half2v*)&vs[dim * 64 + pos * 4 + (kl & 3)] = h;
    }
    __syncthreads();
    const int dim = t >> 2;
    const int q = (t & 3) ^ (dim & 3);
    const _Float16* srow = &vs[dim * 64 + q * 16];
    _Float16* drow = Vt + (size_t)head * HSTRIDE + (size_t)dim * SQ + kt + q * 16;
    *(half8v*)&drow[0] = *(const half8v*)&srow[0];
    *(half8v*)&drow[8] = *(const half8v*)&srow[8];
  }
}

// ---- main (split-K): S^T = K.Q^T via mfma_32x32x16_f16.
// C layout: col=lane&31, row=(reg&3)+8*(reg>>2)+4*(lane>>5). P^T stays in regs.
// __launch_bounds__(256,3): VGPR cap ~170 so acc/sf stay in VGPRs (R9's (256,4)
// clamped VGPR to 64 -> AGPR read/write tax on every softmax op, +220cyc/phase).
// LDS 32 KB dbuf still allows 4 blocks/CU -> 4 waves/SIMD at VGPR<=128.
__global__ __launch_bounds__(256, 3)
void fattn_mfma(const float* __restrict__ Q, const _Float16* __restrict__ Kh,
                const _Float16* __restrict__ Vt, _Float16* __restrict__ Op,
                float2* __restrict__ ML) {
  __shared__ __align__(16) _Float16 kbf[2][BK * 64];
  __shared__ __align__(16) _Float16 vtf[2][HN * 64];

  const int t = threadIdx.x;
  const int lane = t & 63;
  const int w = t >> 6;
  const int h2 = lane >> 5;
  const int l31 = lane & 31;
  const int qb = blockIdx.x * BQ + w * 32;
  const int head = blockIdx.y;
  const int sp = blockIdx.z;
  const int koff = sp * KSPLIT;
  const _Float16* Kp = Kh + (size_t)head * HSTRIDE;
  const _Float16* Vp = Vt + (size_t)head * HSTRIDE;

  // Q B-frags x log2(e): n=query=l31, k=dim=8*h2+j+16*ks
  half8v qf[4];
  {
    const float* qp = Q + (size_t)(qb + l31) * TOK + head * HN + 8 * h2;
    const float s = 1.44269504088896f;
    #pragma unroll
    for (int ks = 0; ks < 4; ++ks) {
      float4 a = *(const float4*)(qp + 16 * ks);
      float4 b = *(const float4*)(qp + 16 * ks + 4);
      half8v f;
      f[0]=(_Float16)(s*a.x); f[1]=(_Float16)(s*a.y); f[2]=(_Float16)(s*a.z); f[3]=(_Float16)(s*a.w);
      f[4]=(_Float16)(s*b.x); f[5]=(_Float16)(s*b.y); f[6]=(_Float16)(s*b.z); f[7]=(_Float16)(s*b.w);
      qf[ks] = f;
    }
  }

  f32x16 acc0, acc1;
  #pragma unroll
  for (int r = 0; r < 16; ++r) { acc0[r] = 0.f; acc1[r] = 0.f; }
  float m_i = -INFINITY, l_i = 0.f;

  auto stage = [&](int p) {     // 16 KB per phase, pure DMA
    const int kt = koff + p * BK;
    const int buf = p & 1;
    #pragma unroll
    for (int i = 0; i < 2; ++i) {
      const int off = w * 1024 + i * 512;
      async16(Kp + (size_t)kt * 64 + off + lane * 8, &kbf[buf][off]);
    }
    #pragma unroll
    for (int i = 0; i < 2; ++i) {
      const int off = w * 1024 + i * 512;
      const int eo = off + lane * 8;
      const int dim = eo >> 6, inner = eo & 63;
      async16(Vp + (size_t)dim * SQ + kt + inner, &vtf[buf][off]);
    }
  };

  stage(0);
  for (int p = 0; p < NPH; ++p) {
    __syncthreads();
    if (p + 1 < NPH) stage(p + 1);
    const int cur = p & 1;

    // ---- S^T = K.Q^T ----
    f32x16 sf0, sf1;
    {
      f32x16 c0, c1;
      #pragma unroll
      for (int r = 0; r < 16; ++r) { c0[r] = 0.f; c1[r] = 0.f; }
      #pragma unroll
      for (int ks = 0; ks < 4; ++ks) {
        const int pos = ((h2 + 2 * ks) ^ (l31 & 7)) * 8;
        half8v a0v = *(const half8v*)&kbf[cur][l31 * 64 + pos];
        half8v a1v = *(const half8v*)&kbf[cur][(l31 + 32) * 64 + pos];
        c0 = __builtin_amdgcn_mfma_f32_32x32x16_f16(a0v, qf[ks], c0, 0, 0, 0);
        c1 = __builtin_amdgcn_mfma_f32_32x32x16_f16(a1v, qf[ks], c1, 0, 0, 0);
      }
      sf0 = c0; sf1 = c1;
    }

    // ---- online softmax (log2 domain) ----
    float mx = -INFINITY;
    #pragma unroll
    for (int r = 0; r < 16; ++r) mx = fmaxf(mx, fmaxf(sf0[r], sf1[r]));
    mx = fmaxf(mx, __shfl_xor(mx, 32, 64));
    const float mnew = fmaxf(m_i, mx);
    const float alpha = fexp2(m_i - mnew);
    float rsum = 0.f;
    #pragma unroll
    for (int r = 0; r < 16; ++r) {
      float p0 = fexp2(sf0[r] - mnew);
      float p1 = fexp2(sf1[r] - mnew);
      sf0[r] = p0; sf1[r] = p1;
      rsum += p0 + p1;
    }
    rsum += __shfl_xor(rsum, 32, 64);
    l_i = l_i * alpha + rsum;
    m_i = mnew;
    #pragma unroll
    for (int r = 0; r < 16; ++r) { acc0[r] *= alpha; acc1[r] *= alpha; }

    // ---- PV: O^T += V^T.P^T, permuted k-order ----
    #pragma unroll
    for (int ks = 0; ks < 4; ++ks) {
      const int rb = 8 * (ks & 1);
      const f32x16& s = (ks < 2) ? sf0 : sf1;
      union { half8v v8; half2v v2[4]; } pu;
      #pragma unroll
      for (int tt = 0; tt < 4; ++tt) {
        auto pk = __builtin_amdgcn_cvt_pkrtz(s[rb + 2 * tt], s[rb + 2 * tt + 1]);
        pu.v2[tt] = *(half2v*)&pk;
      }
      #pragma unroll
      for (int mbd = 0; mbd < 2; ++mbd) {
        const int dim = l31 + 32 * mbd;
        const int sw = dim & 15;
        union { half8v v8; half4v v4[2]; } au;
        au.v4[0] = *(const half4v*)&vtf[cur][dim * 64 + ((4 * ks + h2)     ^ sw) * 4];
        au.v4[1] = *(const half4v*)&vtf[cur][dim * 64 + ((4 * ks + 2 + h2) ^ sw) * 4];
        if (mbd == 0)
          acc0 = __builtin_amdgcn_mfma_f32_32x32x16_f16(au.v8, pu.v8, acc0, 0, 0, 0);
        else
          acc1 = __builtin_amdgcn_mfma_f32_32x32x16_f16(au.v8, pu.v8, acc1, 0, 0, 0);
      }
    }
  }

  // ---- epilogue: unnormalized partial in f16 + (m,l) per query ----
  _Float16* prow = Op + (((size_t)(sp * NBH + head)) * SQ + qb + l31) * HN;
  #pragma unroll
  for (int rq = 0; rq < 4; ++rq) {
    half4v h0, h1;
    #pragma unroll
    for (int j = 0; j < 4; ++j) {
      h0[j] = (_Float16)acc0[4 * rq + j];
      h1[j] = (_Float16)acc1[4 * rq + j];
    }
    *(half4v*)&prow[8 * rq + 4 * h2]      = h0;
    *(half4v*)&prow[32 + 8 * rq + 4 * h2] = h1;
  }
  if (h2 == 0) {
    float2 ml; ml.x = m_i; ml.y = l_i;
    ML[((size_t)(sp * NBH + head)) * SQ + qb + l31] = ml;
  }
}

// ---- merge: O = (A0*w0 + A1*w1) / (l0*w0 + l1*w1), wi = 2^(mi - m) ----
__global__ __launch_bounds__(256)
void merge2(const _Float16* __restrict__ Op, const float2* __restrict__ ML,
            float* __restrict__ O) {
  const int gid = blockIdx.x * 256 + threadIdx.x;
  const int f = gid * 4;
  const int q = f >> 11;
  const int rem = f & 2047;
  const int head = rem >> 6;
  const int d = rem & 63;
  const size_t i0 = (size_t)head * SQ + q;
  const size_t i1 = (size_t)(NBH + head) * SQ + q;
  const float2 ml0 = ML[i0];
  const float2 ml1 = ML[i1];
  const float m = fmaxf(ml0.x, ml1.x);
  const float w0 = fexp2(ml0.x - m);
  const float w1 = fexp2(ml1.x - m);
  const float inv = 1.f / (ml0.y * w0 + ml1.y * w1);
  half4v a0 = *(const half4v*)(Op + i0 * HN + d);
  half4v a1 = *(const half4v*)(Op + i1 * HN + d);
  float4 o;
  o.x = ((float)a0[0] * w0 + (float)a1[0] * w1) * inv;
  o.y = ((float)a0[1] * w0 + (float)a1[1] * w1) * inv;
  o.z = ((float)a0[2] * w0 + (float)a1[2] * w1) * inv;
  o.w = ((float)a0[3] * w0 + (float)a1[3] * w1) * inv;
  *(float4*)(O + f) = o;
}

extern "C" void kernel_launch(void* const* d_in, const int* in_sizes, int n_in,
                              void* d_out, int out_size, void* d_ws, size_t ws_size,
                              hipStream_t stream) {
  const float* Q = (const float*)d_in[0];
  const float* K = (const float*)d_in[1];
  const float* V = (const float*)d_in[2];
  float* O = (float*)d_out;
  _Float16* Kh = (_Float16*)d_ws;                         // 8 MB
  _Float16* Vh = Kh + (size_t)NBH * HSTRIDE;              // 8 MB
  _Float16* Op = Vh + (size_t)NBH * HSTRIDE;              // 16.8 MB
  float2*   ML = (float2*)(Op + (size_t)NSPLIT * NBH * SQ * HN);  // 1 MB
  prep_kv<<<dim3(SQ / 64, NBH), 256, 0, stream>>>(K, V, Kh, Vh);
  fattn_mfma<<<dim3(SQ / BQ, NBH, NSPLIT), 256, 0, stream>>>(Q, Kh, Vh, Op, ML);
  merge2<<<dim3(SQ * NBH * HN / 4 / 256), 256, 0, stream>>>(Op, ML, O);
}